// Round 1
// baseline (503.112 us; speedup 1.0000x reference)
//
#include <hip/hip_runtime.h>
#include <math.h>

#define NF 8192

// ---------- complex helpers ----------
__device__ __forceinline__ int phys(int e) { return e ^ (((e >> 4) & 7) << 1); }

__device__ __forceinline__ float2 cmul(float2 a, float2 b) {
    return make_float2(a.x*b.x - a.y*b.y, a.x*b.y + a.y*b.x);
}
__device__ __forceinline__ float2 cmulc(float2 a, float2 b) { // a * conj(b)
    return make_float2(a.x*b.x + a.y*b.y, a.y*b.x - a.x*b.y);
}
__device__ __forceinline__ float2 cadd(float2 a, float2 b){ return make_float2(a.x+b.x, a.y+b.y); }
__device__ __forceinline__ float2 csub(float2 a, float2 b){ return make_float2(a.x-b.x, a.y-b.y); }
__device__ __forceinline__ float2 mnegi(float2 a){ return make_float2(a.y, -a.x); }   // * (-i)
__device__ __forceinline__ float2 mposi(float2 a){ return make_float2(-a.y, a.x); }   // * (+i)
#define RSQ2 0.70710678118654752f
__device__ __forceinline__ float2 mw81 (float2 a){ return make_float2( RSQ2*(a.x+a.y),  RSQ2*(a.y-a.x)); } // * e^{-i pi/4}
__device__ __forceinline__ float2 mw83 (float2 a){ return make_float2( RSQ2*(a.y-a.x), -RSQ2*(a.x+a.y)); } // * e^{-3i pi/4}
__device__ __forceinline__ float2 mw81c(float2 a){ return make_float2( RSQ2*(a.x-a.y),  RSQ2*(a.x+a.y)); } // * e^{+i pi/4}
__device__ __forceinline__ float2 mw83c(float2 a){ return make_float2(-RSQ2*(a.x+a.y),  RSQ2*(a.x-a.y)); } // * e^{+3i pi/4}

// ---------- radix-8 DIF forward pass (natural -> digit-scrambled) ----------
template<int M, int LM>
__device__ __forceinline__ void fwd8(float2* Z, const float2* __restrict__ tw, int tid) {
    #pragma unroll
    for (int q = 0; q < 4; ++q) {
        int beta = tid + q*256;              // 1024 butterflies
        int i    = beta & (M-1);
        int base = ((beta >> LM) << (LM+3)) + i;
        float2 v0 = Z[phys(base        )];
        float2 v1 = Z[phys(base + 1*M)];
        float2 v2 = Z[phys(base + 2*M)];
        float2 v3 = Z[phys(base + 3*M)];
        float2 v4 = Z[phys(base + 4*M)];
        float2 v5 = Z[phys(base + 5*M)];
        float2 v6 = Z[phys(base + 6*M)];
        float2 v7 = Z[phys(base + 7*M)];
        float2 t;
        // stage 1 (h=4), twiddle w8^j on the (u-v) leg
        t = csub(v0, v4); v0 = cadd(v0, v4); v4 = t;
        t = csub(v1, v5); v1 = cadd(v1, v5); v5 = mw81(t);
        t = csub(v2, v6); v2 = cadd(v2, v6); v6 = mnegi(t);
        t = csub(v3, v7); v3 = cadd(v3, v7); v7 = mw83(t);
        // stage 2 (h=2), twiddle w4^j
        t = csub(v0, v2); v0 = cadd(v0, v2); v2 = t;
        t = csub(v1, v3); v1 = cadd(v1, v3); v3 = mnegi(t);
        t = csub(v4, v6); v4 = cadd(v4, v6); v6 = t;
        t = csub(v5, v7); v5 = cadd(v5, v7); v7 = mnegi(t);
        // stage 3 (h=1)
        t = csub(v0, v1); v0 = cadd(v0, v1); v1 = t;
        t = csub(v2, v3); v2 = cadd(v2, v3); v3 = t;
        t = csub(v4, v5); v4 = cadd(v4, v5); v5 = t;
        t = csub(v6, v7); v6 = cadd(v6, v7); v7 = t;
        // regs now hold [y0,y4,y2,y6,y1,y5,y3,y7]; apply outer twiddle W_{8M}^{i*k}, store at k
        int ts = (NF >> (LM+3)) * i;         // table stride (tw[ts*k] = W^{ik})
        Z[phys(base        )] = v0;
        Z[phys(base + 4*M)] = cmul(v1, tw[ts*4]);
        Z[phys(base + 2*M)] = cmul(v2, tw[ts*2]);
        Z[phys(base + 6*M)] = cmul(v3, tw[ts*6]);
        Z[phys(base + 1*M)] = cmul(v4, tw[ts  ]);
        Z[phys(base + 5*M)] = cmul(v5, tw[ts*5]);
        Z[phys(base + 3*M)] = cmul(v6, tw[ts*3]);
        Z[phys(base + 7*M)] = cmul(v7, tw[ts*7]);
    }
}

// ---------- radix-8 DIT inverse pass (scrambled -> natural), unscaled ----------
template<int M, int LM>
__device__ __forceinline__ void inv8(float2* Z, const float2* __restrict__ tw, int tid) {
    #pragma unroll
    for (int q = 0; q < 4; ++q) {
        int beta = tid + q*256;
        int i    = beta & (M-1);
        int base = ((beta >> LM) << (LM+3)) + i;
        int ts   = (NF >> (LM+3)) * i;
        // load reg p = y_{rev[p]} * conj(W^{i*rev[p]})
        float2 v0 = Z[phys(base        )];
        float2 v1 = cmulc(Z[phys(base + 4*M)], tw[ts*4]);
        float2 v2 = cmulc(Z[phys(base + 2*M)], tw[ts*2]);
        float2 v3 = cmulc(Z[phys(base + 6*M)], tw[ts*6]);
        float2 v4 = cmulc(Z[phys(base + 1*M)], tw[ts  ]);
        float2 v5 = cmulc(Z[phys(base + 5*M)], tw[ts*5]);
        float2 v6 = cmulc(Z[phys(base + 3*M)], tw[ts*3]);
        float2 v7 = cmulc(Z[phys(base + 7*M)], tw[ts*7]);
        float2 t;
        // inverse of stage 3
        t = csub(v0, v1); v0 = cadd(v0, v1); v1 = t;
        t = csub(v2, v3); v2 = cadd(v2, v3); v3 = t;
        t = csub(v4, v5); v4 = cadd(v4, v5); v5 = t;
        t = csub(v6, v7); v6 = cadd(v6, v7); v7 = t;
        // inverse of stage 2: legs j=1 get *conj(w4^1)=+i
        t = v2;        v2 = csub(v0, t); v0 = cadd(v0, t);
        t = mposi(v3); v3 = csub(v1, t); v1 = cadd(v1, t);
        t = v6;        v6 = csub(v4, t); v4 = cadd(v4, t);
        t = mposi(v7); v7 = csub(v5, t); v5 = cadd(v5, t);
        // inverse of stage 1: *conj(w8^j)
        t = v4;        v4 = csub(v0, t); v0 = cadd(v0, t);
        t = mw81c(v5); v5 = csub(v1, t); v1 = cadd(v1, t);
        t = mposi(v6); v6 = csub(v2, t); v2 = cadd(v2, t);
        t = mw83c(v7); v7 = csub(v3, t); v3 = cadd(v3, t);
        Z[phys(base        )] = v0;
        Z[phys(base + 1*M)] = v1;
        Z[phys(base + 2*M)] = v2;
        Z[phys(base + 3*M)] = v3;
        Z[phys(base + 4*M)] = v4;
        Z[phys(base + 5*M)] = v5;
        Z[phys(base + 6*M)] = v6;
        Z[phys(base + 7*M)] = v7;
    }
}

// final forward radix-2 pass (for kernel-spectrum FFT)
__device__ __forceinline__ void fwd2(float2* Z, int tid) {
    #pragma unroll
    for (int q = 0; q < 16; ++q) {
        int beta = tid + q*256;
        int pe = phys(2*beta);               // even; pair is adjacent & 16B aligned
        float4 z = *reinterpret_cast<float4*>(&Z[pe]);
        float2 u = make_float2(z.x, z.y), w = make_float2(z.z, z.w);
        float2 p = cadd(u, w), r = csub(u, w);
        *reinterpret_cast<float4*>(&Z[pe]) = make_float4(p.x, p.y, r.x, r.y);
    }
}

// fused: forward radix-2 (m=1) -> pointwise *A (scrambled order) -> inverse radix-2
__device__ __forceinline__ void fused_mul(float2* Z, const float4* __restrict__ A4, int tid) {
    #pragma unroll
    for (int q = 0; q < 16; ++q) {
        int beta = tid + q*256;
        int pe = phys(2*beta);
        float4 z = *reinterpret_cast<float4*>(&Z[pe]);
        float2 u = make_float2(z.x, z.y), w = make_float2(z.z, z.w);
        float2 p = cadd(u, w), r = csub(u, w);
        float4 a = A4[beta];                 // coalesced 16B
        p = cmul(p, make_float2(a.x, a.y));
        r = cmul(r, make_float2(a.z, a.w));
        float2 o0 = cadd(p, r), o1 = csub(p, r);
        *reinterpret_cast<float4*>(&Z[pe]) = make_float4(o0.x, o0.y, o1.x, o1.y);
    }
}

// ---------- kernels ----------
__global__ void twiddle_kernel(float2* __restrict__ tw) {
    int j = blockIdx.x * 256 + threadIdx.x;
    double ang = -6.283185307179586476925286766559 * (double)j / 8192.0;
    tw[j] = make_float2((float)cos(ang), (float)sin(ang));
}

// Position-MLP: a[c][e] = decay(e) * rpe(offset(e))[c],  c = h*64+d,  e in [0,8192)
__global__ __launch_bounds__(256) void rpe_kernel(
    const float* __restrict__ pw,  const float* __restrict__ pb,
    const float* __restrict__ lws, const float* __restrict__ lbs,
    const float* __restrict__ ow,  const float* __restrict__ ob,
    float* __restrict__ a_buf)
{
    __shared__ float sW[3][64][64];     // 48 KB (reused as out_w chunk in phase 2)
    __shared__ float sAct[4][4][64];    // final activations: [wave][pos][feat]
    __shared__ float sTmp[4][64];
    __shared__ float sB[3][64];
    __shared__ float sPW[64], sPB[64];
    int tid = threadIdx.x;
    for (int idx = tid; idx < 3*64*64; idx += 256) ((float*)sW)[idx] = lws[idx];
    if (tid < 3*64) ((float*)sB)[tid] = lbs[tid];
    if (tid < 64) { sPW[tid] = pw[tid]; sPB[tid] = pb[tid]; }
    __syncthreads();

    int wave = tid >> 6, lane = tid & 63;
    int ebase = blockIdx.x * 16 + wave * 4;
    float dec[4];
    #pragma unroll
    for (int s = 0; s < 4; ++s) {
        int e = ebase + s;
        // a = concat([rpe(0), g^k rpe(k) k=1..n-1, rpe(0), g^m rpe(-m) m=n-1..1])
        float p = (e == 4096) ? 0.f : ((e < 4096) ? (float)e : (float)(e - 8192));
        int m = (e < 4096) ? e : (8192 - e);
        if (e == 4096) m = 0;
        dec[s] = exp2f(-0.0014434309482562475f * (float)m);   // log2(0.999)
        float xv = fmaf(p, sPW[lane], sPB[lane]);
        for (int L = 0; L < 3; ++L) {
            float ss = xv * xv;
            #pragma unroll
            for (int o = 1; o < 64; o <<= 1) ss += __shfl_xor(ss, o);
            float act = xv / (sqrtf(ss) * 0.125f + 1e-8f);    // SimpleRMSNorm
            act = fmaxf(act, 0.f);                            // relu
            sTmp[wave][lane] = act;
            __syncthreads();
            float y0 = sB[L][lane], y1 = 0.f;
            #pragma unroll
            for (int k = 0; k < 64; k += 2) {
                y0 = fmaf(sTmp[wave][k],   sW[L][k][lane],   y0);
                y1 = fmaf(sTmp[wave][k+1], sW[L][k+1][lane], y1);
            }
            __syncthreads();
            xv = y0 + y1;
        }
        float ss = xv * xv;
        #pragma unroll
        for (int o = 1; o < 64; o <<= 1) ss += __shfl_xor(ss, o);
        float act = xv / (sqrtf(ss) * 0.125f + 1e-8f);
        sAct[wave][s][lane] = fmaxf(act, 0.f);
    }
    // phase 2: out projection in chunks of 64 output channels, weights staged in LDS
    auto& sWo = sW[0];
    for (int qq = 0; qq < 8; ++qq) {
        __syncthreads();
        for (int idx = tid; idx < 4096; idx += 256)
            sWo[idx >> 6][idx & 63] = ow[(size_t)(idx >> 6)*512 + qq*64 + (idx & 63)];
        __syncthreads();
        #pragma unroll
        for (int s = 0; s < 4; ++s) {
            float y0 = ob[qq*64 + lane], y1 = 0.f, y2 = 0.f, y3 = 0.f;
            #pragma unroll
            for (int k = 0; k < 64; k += 4) {
                y0 = fmaf(sAct[wave][s][k],   sWo[k  ][lane], y0);
                y1 = fmaf(sAct[wave][s][k+1], sWo[k+1][lane], y1);
                y2 = fmaf(sAct[wave][s][k+2], sWo[k+2][lane], y2);
                y3 = fmaf(sAct[wave][s][k+3], sWo[k+3][lane], y3);
            }
            int e = ebase + s;
            a_buf[(size_t)(qq*64 + lane)*NF + e] = (y0+y1+y2+y3) * dec[s];
        }
    }
}

// FFT of each kernel column, stored in scrambled (post-pass) order
__global__ __launch_bounds__(256, 2) void afft_kernel(
    const float* __restrict__ a_buf, const float2* __restrict__ tw,
    float2* __restrict__ Afft)
{
    __shared__ float2 Z[NF];             // 64 KB
    int cc = blockIdx.x, tid = threadIdx.x;
    const float* col = a_buf + (size_t)cc * NF;
    #pragma unroll
    for (int j = 0; j < 32; ++j) { int e = tid + j*256; Z[phys(e)] = make_float2(col[e], 0.f); }
    __syncthreads();
    fwd8<1024,10>(Z, tw, tid); __syncthreads();
    fwd8<128, 7>(Z, tw, tid);  __syncthreads();
    fwd8<16,  4>(Z, tw, tid);  __syncthreads();
    fwd8<2,   1>(Z, tw, tid);  __syncthreads();
    fwd2(Z, tid);              __syncthreads();
    float2* oc = Afft + (size_t)cc * NF;
    #pragma unroll
    for (int j = 0; j < 32; ++j) { int e = tid + j*256; oc[e] = Z[phys(e)]; }
}

// main conv: z = x[2bp] + i*x[2bp+1] (same h,d) -> FFT -> *A -> IFFT
__global__ __launch_bounds__(256, 2) void conv_kernel(
    const float* __restrict__ x, const float2* __restrict__ tw,
    const float2* __restrict__ Afft, float* __restrict__ out)
{
    __shared__ float2 Z[NF];             // 64 KB -> 2 blocks/CU
    int blk = blockIdx.x;
    // XCD-aware decode: blockIdx%8 selects (d-half, h-parity, bp-parity) so each XCD
    // gets contiguous 32-d slices of each (b,h) slab -> full-line L2 sharing.
    int c = blk & 7, r = blk >> 3;
    int d  = ((c & 1) << 5) | (r & 31);
    int h  = (((r >> 5) & 3) << 1) | ((c >> 1) & 1);
    int bp = (((r >> 7) & 1) << 1) | ((c >> 2) & 1);
    int tid = threadIdx.x;
    size_t base0 = ((size_t)((bp*2 + 0)*8 + h) * 4096) * 64 + d;
    size_t base1 = ((size_t)((bp*2 + 1)*8 + h) * 4096) * 64 + d;
    #pragma unroll
    for (int j = 0; j < 16; ++j) {
        int t = tid + j*256;
        float re = x[base0 + (size_t)t*64];
        float im = x[base1 + (size_t)t*64];
        Z[phys(t)]        = make_float2(re, im);
        Z[phys(t + 4096)] = make_float2(0.f, 0.f);
    }
    __syncthreads();
    fwd8<1024,10>(Z, tw, tid); __syncthreads();
    fwd8<128, 7>(Z, tw, tid);  __syncthreads();
    fwd8<16,  4>(Z, tw, tid);  __syncthreads();
    fwd8<2,   1>(Z, tw, tid);  __syncthreads();
    const float4* A4 = reinterpret_cast<const float4*>(Afft + (size_t)(h*64 + d)*NF);
    fused_mul(Z, A4, tid);     __syncthreads();
    inv8<2,   1>(Z, tw, tid);  __syncthreads();
    inv8<16,  4>(Z, tw, tid);  __syncthreads();
    inv8<128, 7>(Z, tw, tid);  __syncthreads();
    inv8<1024,10>(Z, tw, tid); __syncthreads();
    const float sc = 1.0f/8192.0f;
    #pragma unroll
    for (int j = 0; j < 16; ++j) {
        int t = tid + j*256;
        float2 v = Z[phys(t)];
        out[base0 + (size_t)t*64] = v.x * sc;
        out[base1 + (size_t)t*64] = v.y * sc;
    }
}

extern "C" void kernel_launch(void* const* d_in, const int* in_sizes, int n_in,
                              void* d_out, int out_size, void* d_ws, size_t ws_size,
                              hipStream_t stream) {
    const float* x   = (const float*)d_in[0];
    const float* pw  = (const float*)d_in[1];
    const float* pb  = (const float*)d_in[2];
    const float* lws = (const float*)d_in[3];
    const float* lbs = (const float*)d_in[4];
    const float* ow  = (const float*)d_in[5];
    const float* ob  = (const float*)d_in[6];
    float* out = (float*)d_out;
    char* ws = (char*)d_ws;
    // ws layout: [0,64K) twiddles | [64K, 64K+16M) a_buf | [.., +32M) Afft  (~48.1 MB total)
    float2* tw    = (float2*)ws;
    float*  a_buf = (float*)(ws + 65536);
    float2* Afft  = (float2*)(ws + 65536 + (size_t)512*NF*4);

    twiddle_kernel<<<32, 256, 0, stream>>>(tw);
    rpe_kernel<<<512, 256, 0, stream>>>(pw, pb, lws, lbs, ow, ob, a_buf);
    afft_kernel<<<512, 256, 0, stream>>>(a_buf, tw, Afft);
    conv_kernel<<<2048, 256, 0, stream>>>(x, tw, Afft, out);
}